// Round 14
// baseline (408.847 us; speedup 1.0000x reference)
//
#include <hip/hip_runtime.h>
#include <math.h>

#define N_WORD 50000
#define N_DOC  10000
#define E_WW   800000
#define E_WD   320000
#define D_IN   256
#define D_H    128

#define NPB    256            // nodes per bucket
#define NBK_W  196            // ceil(50000/256)
#define NBK_D  40             // ceil(10000/256)
#define BKT    (3 * NBK_W + NBK_D)   // 628 buckets total
#define EPB    4096           // edges per block in bin
#define NBLK_WW 196           // ceil(800000/4096)
#define NBLK_WD 79            // ceil(320000/4096)
#define NBLK_TOT (2 * NBLK_WW + 2 * NBLK_WD)   // 550
#define PACK_BLKS 145

// per-bucket staging caps (binomial mean + >10 sigma; graph fixed by seed)
#define CAP_WW  4736          // mean 4082, sigma ~64
#define CAP_WDR 2176          // mean 1633, sigma ~40
#define CAP_WD  8960          // mean 8000, sigma ~89

#define WSTRIP ((N_WORD + 63) / 64)  // 782
#define DSTRIP ((N_DOC + 63) / 64)   // 157
#define NSTRIP (WSTRIP + DSTRIP)     // 939

typedef __attribute__((ext_vector_type(8))) short short8;
typedef __attribute__((ext_vector_type(4))) float f32x4;

__device__ inline unsigned short f2bf(float f) {  // fp32 -> bf16 bits, RNE
  unsigned u = __float_as_uint(f);
  u = (u + 0x7fffu + ((u >> 16) & 1u)) >> 16;
  return (unsigned short)u;
}

// ---------------- GEMM body: register-resident A fragments, no LDS ----------
struct G6 { const short* B[6]; unsigned short* C[6]; };

template <int ABF, int K>
__device__ void gemm_body(const void* __restrict__ Aw, const void* __restrict__ Ad,
                          const G6& g, int blk) {
  constexpr int KT = K >> 5;
  int wid = threadIdx.x >> 6, lane = threadIdx.x & 63;
  const void* A; int M, row0, h0, h1;
  if (blk < WSTRIP) { A = Aw; M = N_WORD; row0 = blk << 6; h0 = 0; h1 = 4; }
  else { A = Ad; M = N_DOC; row0 = (blk - WSTRIP) << 6; h0 = 4; h1 = 6; }
  int r = lane & 15, quad = lane >> 4;
  int m0 = row0 + wid * 16;
  int mA = m0 + r; if (mA >= M) mA = M - 1;   // clamp: garbage rows never stored
  short8 afr[KT];
  if (ABF) {
    const short* ap = (const short*)A + (size_t)mA * K + quad * 8;
#pragma unroll
    for (int kt = 0; kt < KT; ++kt) afr[kt] = *(const short8*)(ap + kt * 32);
  } else {
    const float* ap = (const float*)A + (size_t)mA * K + quad * 8;
#pragma unroll
    for (int kt = 0; kt < KT; ++kt) {
      float4 a0 = *(const float4*)(ap + kt * 32);
      float4 a1 = *(const float4*)(ap + kt * 32 + 4);
      short8 v;
      v[0] = (short)f2bf(a0.x); v[1] = (short)f2bf(a0.y);
      v[2] = (short)f2bf(a0.z); v[3] = (short)f2bf(a0.w);
      v[4] = (short)f2bf(a1.x); v[5] = (short)f2bf(a1.y);
      v[6] = (short)f2bf(a1.z); v[7] = (short)f2bf(a1.w);
      afr[kt] = v;
    }
  }
  for (int h = h0; h < h1; ++h) {
    const short* Bp = g.B[h];
    f32x4 acc[8];
#pragma unroll
    for (int nt = 0; nt < 8; ++nt) acc[nt] = (f32x4){0.f, 0.f, 0.f, 0.f};
#pragma unroll
    for (int kt = 0; kt < KT; ++kt) {
      const short* bbase = Bp + ((size_t)kt * 4096) + lane * 8;
#pragma unroll
      for (int nt = 0; nt < 8; ++nt) {
        short8 bf = *(const short8*)(bbase + (size_t)nt * 512);
        acc[nt] = __builtin_amdgcn_mfma_f32_16x16x32_bf16(afr[kt], bf, acc[nt], 0, 0, 0);
      }
    }
    // C/D: col = lane&15, row = quad*4 + rr  [m89-verified]
    unsigned short* C = g.C[h];
#pragma unroll
    for (int nt = 0; nt < 8; ++nt)
#pragma unroll
      for (int rr = 0; rr < 4; ++rr) {
        int row = m0 + quad * 4 + rr;
        if (row < M) C[(size_t)row * 128 + nt * 16 + r] = f2bf(acc[nt][rr]);
      }
  }
}

// ---------------- prep: weight pack + bias combine + bcnt zero ---------------
__global__ __launch_bounds__(256) void prep_kernel(
    const float* __restrict__ Ws1, const float* __restrict__ Wn1,
    const float* __restrict__ Ws2, const float* __restrict__ Wn2,
    short* __restrict__ Bp1, short* __restrict__ Bp2,
    const float* __restrict__ b1, const float* __restrict__ b2,
    float* __restrict__ bs1, float* __restrict__ bs2, int* __restrict__ bcnt) {
  int b = blockIdx.x;
  if (b == PACK_BLKS) {               // zero block
    for (int i = threadIdx.x; i < BKT; i += 256) bcnt[i] = 0;
    return;
  }
  int tid = b * 256 + threadIdx.x;
  const int L1T = 6 * 4096;
  const int L2T = 6 * 2048;
  if (tid >= L1T + L2T) {             // bias combine tail
    int t = tid - (L1T + L2T);
    if (t < 128) bs1[t] = b1[t] + b1[128 + t] + b1[384 + t];
    else if (t < 256) { int u = t - 128; bs2[u] = b2[u] + b2[128 + u] + b2[384 + u]; }
    return;
  }
  const float *src0, *src1 = nullptr, *src2 = nullptr;
  short* dstp;
  int kt, nt, lane;
  if (tid < L1T) {
    int mat = tid / 4096, rem = tid % 4096;
    kt = rem / 512; nt = (rem / 64) % 8; lane = rem % 64;
    const int W1 = 256 * 128;
    if (mat == 0) { src0 = Ws1; src1 = Ws1 + W1; src2 = Ws1 + 3 * W1; }
    else if (mat <= 4) src0 = Wn1 + (size_t)(mat - 1) * W1;
    else src0 = Ws1 + 2 * W1;
    dstp = Bp1 + (size_t)mat * W1 + ((size_t)(kt * 8 + nt) * 64 + lane) * 8;
  } else {
    int t2 = tid - L1T;
    int mat = t2 / 2048, rem = t2 % 2048;
    kt = rem / 512; nt = (rem / 64) % 8; lane = rem % 64;
    const int W2 = 128 * 128;
    if (mat == 0) { src0 = Ws2; src1 = Ws2 + W2; src2 = Ws2 + 3 * W2; }
    else if (mat <= 4) src0 = Wn2 + (size_t)(mat - 1) * W2;
    else src0 = Ws2 + 2 * W2;
    dstp = Bp2 + (size_t)mat * W2 + ((size_t)(kt * 8 + nt) * 64 + lane) * 8;
  }
  int n = nt * 16 + (lane & 15);
  int kb = kt * 32 + (lane >> 4) * 8;
  short8 v;
#pragma unroll
  for (int j = 0; j < 8; ++j) {
    float f = src0[(size_t)(kb + j) * 128 + n];
    if (src1) f += src1[(size_t)(kb + j) * 128 + n] + src2[(size_t)(kb + j) * 128 + n];
    v[j] = (short)f2bf(f);
  }
  *(short8*)dstp = v;
}

// ---------------- fused bin || layer-1 GEMM ----------------------------------
// blocks [0, NBLK_TOT): bin edges into staging; [NBLK_TOT, +NSTRIP): gemm1.
// Independent: bin writes staging (yB0/yB1 aliases) + bcnt; gemm1 writes
// twA/tdA/yB2/xw1B/yBX/ydB and reads xw/xd/Bp1 (prep done in prior dispatch).
__device__ inline void rel_map(int b, const int* wwd, const int* wwrd, const int* wdrd,
                               const int* wdd, const int*& dst, int& E, int& gbase, int& lb) {
  if (b < NBLK_WW) { dst = wwd; E = E_WW; gbase = 0; lb = b; }
  else if (b < 2 * NBLK_WW) { dst = wwrd; E = E_WW; gbase = NBK_W; lb = b - NBLK_WW; }
  else if (b < 2 * NBLK_WW + NBLK_WD) { dst = wdrd; E = E_WD; gbase = 2 * NBK_W; lb = b - 2 * NBLK_WW; }
  else { dst = wdd; E = E_WD; gbase = 3 * NBK_W; lb = b - 2 * NBLK_WW - NBLK_WD; }
}

__global__ __launch_bounds__(256, 4) void bin_gemm1(
    const int* wws, const int* wwd, const int* wwrs, const int* wwrd,
    const int* wdrs, const int* wdrd, const int* wds, const int* wdd,
    int* bcnt, unsigned* st_ww, unsigned* st_wwr, unsigned* st_wdr, unsigned* st_wd,
    const float* __restrict__ Aw, const float* __restrict__ Ad, G6 g) {
  __shared__ int h[4][NBK_W], wb[4][NBK_W], cur[4][NBK_W];   // 9.4 KB (bin only)
  int b = blockIdx.x;
  if (b >= NBLK_TOT) {
    gemm_body<0, 256>(Aw, Ad, g, b - NBLK_TOT);
    return;
  }
  // ---------- bin: per-wave hist -> per-wave reservation -> scatter ----------
  const int* dst; int E, gbase, lb;
  rel_map(b, wwd, wwrd, wdrd, wdd, dst, E, gbase, lb);
  const int* src; unsigned* st; int cap;
  if (b < NBLK_WW) { src = wws; st = st_ww; cap = CAP_WW; }
  else if (b < 2 * NBLK_WW) { src = wwrs; st = st_wwr; cap = CAP_WW; }
  else if (b < 2 * NBLK_WW + NBLK_WD) { src = wdrs; st = st_wdr; cap = CAP_WDR; }
  else { src = wds; st = st_wd; cap = CAP_WD; }
  int tid = threadIdx.x;
  int wave = tid >> 6;
  for (int i = tid; i < 4 * NBK_W; i += 256) { ((int*)h)[i] = 0; ((int*)cur)[i] = 0; }
  __syncthreads();
  int e0 = lb * EPB;
  int dcache[EPB / 256];              // dst cached across passes (16 VGPRs)
#pragma unroll
  for (int k = 0; k < EPB / 256; ++k) {
    int i = e0 + k * 256 + tid;
    int d = (i < E) ? dst[i] : -1;
    dcache[k] = d;
    if (d >= 0) atomicAdd(&h[wave][d >> 8], 1);
  }
  __syncthreads();
  if (tid < NBK_W) {
    int t0 = h[0][tid], t1 = h[1][tid], t2 = h[2][tid], t3 = h[3][tid];
    int tot = t0 + t1 + t2 + t3;
    int base = tot ? atomicAdd(&bcnt[gbase + tid], tot) : 0;
    wb[0][tid] = base;
    wb[1][tid] = base + t0;
    wb[2][tid] = base + t0 + t1;
    wb[3][tid] = base + t0 + t1 + t2;
  }
  __syncthreads();
#pragma unroll
  for (int k = 0; k < EPB / 256; ++k) {
    int d = dcache[k];
    if (d >= 0) {
      int i = e0 + k * 256 + tid;
      int bk = d >> 8;
      int l = atomicAdd(&cur[wave][bk], 1);
      st[(size_t)bk * cap + wb[wave][bk] + l] =
          (unsigned)(src[i] & 0xFFFF) | ((unsigned)(d & (NPB - 1)) << 16);
    }
  }
}

// ---------------- place: one block per 256-node bucket -----------------------
struct CSRB {
  const unsigned *st_ww, *st_wwr, *st_wdr, *st_wd;
  unsigned short *c_ww, *c_wwr, *c_wdr, *c_wd;
  int *rp_ww, *rp_wwr, *rp_wdr, *rp_wd;
  const int* bcnt;
};

__global__ __launch_bounds__(256) void place_kernel(CSRB q) {
  __shared__ int cnt[256], off[256], sm[256];
  int g = blockIdx.x;
  const unsigned* st; unsigned short* csr; int* rp; int relFirst, relLast, n, cap, Etot;
  if (g < NBK_W)            { st = q.st_ww;  csr = q.c_ww;  rp = q.rp_ww;  relFirst = 0;         relLast = NBK_W - 1;     n = N_WORD; cap = CAP_WW;  Etot = E_WW; }
  else if (g < 2 * NBK_W)   { st = q.st_wwr; csr = q.c_wwr; rp = q.rp_wwr; relFirst = NBK_W;     relLast = 2 * NBK_W - 1; n = N_WORD; cap = CAP_WW;  Etot = E_WW; }
  else if (g < 3 * NBK_W)   { st = q.st_wdr; csr = q.c_wdr; rp = q.rp_wdr; relFirst = 2 * NBK_W; relLast = 3 * NBK_W - 1; n = N_WORD; cap = CAP_WDR; Etot = E_WD; }
  else                      { st = q.st_wd;  csr = q.c_wd;  rp = q.rp_wd;  relFirst = 3 * NBK_W; relLast = BKT - 1;       n = N_DOC;  cap = CAP_WD;  Etot = E_WD; }
  int cb = g - relFirst;
  int tid = threadIdx.x;
  // segment-exclusive prefix of bcnt over [relFirst, g): block tree-reduce
  int v = (tid < cb) ? q.bcnt[relFirst + tid] : 0;
  sm[tid] = v;
  __syncthreads();
  for (int o = 128; o > 0; o >>= 1) {
    if (tid < o) sm[tid] += sm[tid + o];
    __syncthreads();
  }
  int bstart = sm[0];
  if (g == relLast && tid == 0) rp[n] = Etot;   // tail sentinel
  __syncthreads();                               // sm reuse below
  int node_base = cb << 8;
  int node_cnt = n - node_base; if (node_cnt > NPB) node_cnt = NPB;
  int ecnt = q.bcnt[g];
  const unsigned* w = st + (size_t)cb * cap;
  cnt[tid] = 0;
  __syncthreads();
  for (int j = tid; j < ecnt; j += 256) atomicAdd(&cnt[w[j] >> 16], 1);
  __syncthreads();
  int c = cnt[tid];
  sm[tid] = c;
  __syncthreads();
  for (int o = 1; o < 256; o <<= 1) {
    int add = (tid >= o) ? sm[tid - o] : 0;
    __syncthreads();
    sm[tid] += add;
    __syncthreads();
  }
  int ex = sm[tid] - c;
  off[tid] = ex;
  if (tid < node_cnt) rp[node_base + tid] = bstart + ex;
  __syncthreads();
  for (int j = tid; j < ecnt; j += 256) {
    unsigned e = w[j];
    int p = atomicAdd(&off[e >> 16], 1);
    csr[bstart + p] = (unsigned short)(e & 0xFFFFu);
  }
}

__global__ __launch_bounds__(256, 6) void gemm2_kernel(
    const void* __restrict__ Aw, const void* __restrict__ Ad, G6 g) {
  gemm_body<1, 128>(Aw, Ad, g, blockIdx.x);
}

// ---------------- merged gather: readlane scalar-base loads, 8-deep MLP ------
__device__ inline void accum_rel(const unsigned* __restrict__ y,
                                 const unsigned short* __restrict__ csr,
                                 int beg, int end, int lane, float& f0, float& f1) {
  float a0 = 0.f, a1 = 0.f;
  for (int base = beg; base < end; base += 64) {
    int cnt = end - base; if (cnt > 64) cnt = 64;
    int ld = base + lane; if (ld >= end) ld = end - 1;
    int idx = csr[ld];                 // 64 indices per coalesced 128B load
    int j = 0;
    for (; j + 7 < cnt; j += 8) {      // 8 loads in flight
      unsigned u[8];
#pragma unroll
      for (int k = 0; k < 8; ++k) {
        int s = __builtin_amdgcn_readlane(idx, j + k);   // SGPR row -> scalar base
        u[k] = y[((size_t)s << 6) + lane];
      }
#pragma unroll
      for (int k = 0; k < 8; ++k) {
        a0 += __uint_as_float(u[k] << 16);
        a1 += __uint_as_float(u[k] & 0xffff0000u);
      }
    }
    for (; j < cnt; ++j) {
      int s = __builtin_amdgcn_readlane(idx, j);
      unsigned uu = y[((size_t)s << 6) + lane];
      a0 += __uint_as_float(uu << 16);
      a1 += __uint_as_float(uu & 0xffff0000u);
    }
  }
  int deg = end - beg;
  float inv = 1.0f / (float)(deg > 1 ? deg : 1);
  f0 += a0 * inv;
  f1 += a1 * inv;
}

// mode 1: write bf16 activations; mode 2: fused linear+sigmoid readout.
__global__ __launch_bounds__(256) void gather_all(
    const unsigned* __restrict__ y_ww, const unsigned* __restrict__ y_wwr,
    const unsigned* __restrict__ y_wdr, const unsigned* __restrict__ y_wd,
    const unsigned short* __restrict__ c_ww, const unsigned short* __restrict__ c_wwr,
    const unsigned short* __restrict__ c_wdr, const unsigned short* __restrict__ c_wd,
    const int* __restrict__ r_ww, const int* __restrict__ r_wwr,
    const int* __restrict__ r_wdr, const int* __restrict__ r_wd,
    const unsigned* __restrict__ tW, const unsigned* __restrict__ tD,
    const float* __restrict__ bW, const float* __restrict__ bD,
    const float* __restrict__ lw, const float* __restrict__ lb,
    unsigned* __restrict__ oW16, unsigned* __restrict__ oD16,
    float* __restrict__ oF, int mode) {
  int gn = (blockIdx.x << 2) + (threadIdx.x >> 6);
  if (gn >= N_WORD + N_DOC) return;
  int lane = threadIdx.x & 63;
  float f0, f1;
  if (gn < N_WORD) {
    int node = gn;
    unsigned tu = tW[((size_t)node << 6) + lane];     // bf16 self term
    f0 = __uint_as_float(tu << 16);
    f1 = __uint_as_float(tu & 0xffff0000u);
    accum_rel(y_ww, c_ww, r_ww[node], r_ww[node + 1], lane, f0, f1);
    accum_rel(y_wwr, c_wwr, r_wwr[node], r_wwr[node + 1], lane, f0, f1);
    accum_rel(y_wdr, c_wdr, r_wdr[node], r_wdr[node + 1], lane, f0, f1);
    float2 bv = ((const float2*)bW)[lane];
    f0 = fmaxf(f0 + bv.x, 0.f);
    f1 = fmaxf(f1 + bv.y, 0.f);
    if (mode == 1) {
      oW16[((size_t)node << 6) + lane] = (unsigned)f2bf(f0) | ((unsigned)f2bf(f1) << 16);
    } else {
      float2 lv = ((const float2*)lw)[lane];
      float s = f0 * lv.x + f1 * lv.y;
#pragma unroll
      for (int off = 32; off > 0; off >>= 1) s += __shfl_xor(s, off);
      if (lane == 0) oF[node] = 1.0f / (1.0f + expf(-(s + lb[0])));
    }
  } else {
    int node = gn - N_WORD;
    unsigned tu = tD[((size_t)node << 6) + lane];
    f0 = __uint_as_float(tu << 16);
    f1 = __uint_as_float(tu & 0xffff0000u);
    accum_rel(y_wd, c_wd, r_wd[node], r_wd[node + 1], lane, f0, f1);
    float2 bv = ((const float2*)bD)[lane];
    f0 = fmaxf(f0 + bv.x, 0.f);
    f1 = fmaxf(f1 + bv.y, 0.f);
    if (mode == 1) {
      oD16[((size_t)node << 6) + lane] = (unsigned)f2bf(f0) | ((unsigned)f2bf(f1) << 16);
    } else {
      float2 lv = ((const float2*)lw)[lane];
      float s = f0 * lv.x + f1 * lv.y;
#pragma unroll
      for (int off = 32; off > 0; off >>= 1) s += __shfl_xor(s, off);
      if (lane == 0) oF[N_WORD + node] = 1.0f / (1.0f + expf(-(s + lb[0])));
    }
  }
}

// ---------------------------------------------------------------------------
extern "C" void kernel_launch(void* const* d_in, const int* in_sizes, int n_in,
                              void* d_out, int out_size, void* d_ws, size_t ws_size,
                              hipStream_t stream) {
  const float* xw      = (const float*)d_in[0];
  const float* xd      = (const float*)d_in[1];
  const int*   ww_src  = (const int*)d_in[2];
  const int*   ww_dst  = (const int*)d_in[3];
  const int*   wwr_src = (const int*)d_in[4];
  const int*   wwr_dst = (const int*)d_in[5];
  const int*   wd_src  = (const int*)d_in[6];
  const int*   wd_dst  = (const int*)d_in[7];
  const int*   wdr_src = (const int*)d_in[8];
  const int*   wdr_dst = (const int*)d_in[9];
  const float* Ws1     = (const float*)d_in[10];
  const float* Wn1     = (const float*)d_in[11];
  const float* b1      = (const float*)d_in[12];
  const float* Ws2     = (const float*)d_in[13];
  const float* Wn2     = (const float*)d_in[14];
  const float* b2      = (const float*)d_in[15];
  const float* lin_w   = (const float*)d_in[16];
  const float* lin_b   = (const float*)d_in[17];
  float* out = (float*)d_out;

  // ---- workspace carve (~91 MB; staging aliases yB0/yB1 pre-place) ----
  char* p = (char*)d_ws;
  auto alloc = [&](size_t nbytes) {
    char* r = p;
    p += (nbytes + 255) & ~(size_t)255;
    return r;
  };
  unsigned* twA  = (unsigned*)alloc((size_t)N_WORD * D_H * 2);  // bf16 self acc
  unsigned* tdA  = (unsigned*)alloc((size_t)N_DOC * D_H * 2);
  unsigned* xw1B = (unsigned*)alloc((size_t)N_WORD * D_H * 2);
  unsigned* xd1B = (unsigned*)alloc((size_t)N_DOC * D_H * 2);
  unsigned* yB0 = (unsigned*)alloc((size_t)N_WORD * D_H * 2);
  unsigned* yB1 = (unsigned*)alloc((size_t)N_WORD * D_H * 2);
  unsigned* yB2 = (unsigned*)alloc((size_t)N_WORD * D_H * 2);
  unsigned* ydB = (unsigned*)alloc((size_t)N_DOC * D_H * 2);
  unsigned short* csr_ww  = (unsigned short*)alloc((size_t)E_WW * 2);
  unsigned short* csr_wwr = (unsigned short*)alloc((size_t)E_WW * 2);
  unsigned short* csr_wdr = (unsigned short*)alloc((size_t)E_WD * 2);
  unsigned short* csr_wd  = (unsigned short*)alloc((size_t)E_WD * 2);
  int* rp_ww  = (int*)alloc((size_t)(N_WORD + 1) * 4);
  int* rp_wwr = (int*)alloc((size_t)(N_WORD + 1) * 4);
  int* rp_wdr = (int*)alloc((size_t)(N_WORD + 1) * 4);
  int* rp_wd  = (int*)alloc((size_t)(N_DOC + 1) * 4);
  short* Bp1 = (short*)alloc((size_t)6 * 256 * 128 * 2);
  short* Bp2 = (short*)alloc((size_t)6 * 128 * 128 * 2);
  int* bcnt  = (int*)alloc((size_t)BKT * 4);
  float* bs1 = (float*)alloc(D_H * 4);
  float* bs2 = (float*)alloc(D_H * 4);
  unsigned* yBX = (unsigned*)alloc((size_t)N_WORD * D_H * 2);   // wd-neigh out
  // staging aliases (read by place; dead before gather1 writes yB0)
  unsigned* st_ww  = yB0;
  unsigned* st_wwr = st_ww + (size_t)NBK_W * CAP_WW;
  unsigned* st_wdr = yB1;
  unsigned* st_wd  = st_wdr + (size_t)NBK_W * CAP_WDR;

  const int W1 = 256 * 128;
  const int W2 = 128 * 128;

  // ---- D1: prep (pack + bias + bcnt zero) ----
  prep_kernel<<<PACK_BLKS + 1, 256, 0, stream>>>(
      Ws1, Wn1, Ws2, Wn2, Bp1, Bp2, b1, b2, bs1, bs2, bcnt);

  // ---- D2: bin || layer-1 GEMM (independent; bin blocks first) ----
  G6 g1;
  g1.B[0] = Bp1 + 0 * W1; g1.C[0] = (unsigned short*)twA;   // word self
  g1.B[1] = Bp1 + 1 * W1; g1.C[1] = (unsigned short*)yB2;   // ww neigh
  g1.B[2] = Bp1 + 2 * W1; g1.C[2] = (unsigned short*)xw1B;  // wwr neigh
  g1.B[3] = Bp1 + 3 * W1; g1.C[3] = (unsigned short*)yBX;   // wd neigh
  g1.B[4] = Bp1 + 5 * W1; g1.C[4] = (unsigned short*)tdA;   // doc self
  g1.B[5] = Bp1 + 4 * W1; g1.C[5] = (unsigned short*)ydB;   // wdr neigh
  bin_gemm1<<<NBLK_TOT + NSTRIP, 256, 0, stream>>>(
      ww_src, ww_dst, wwr_src, wwr_dst, wdr_src, wdr_dst, wd_src, wd_dst,
      bcnt, st_ww, st_wwr, st_wdr, st_wd, xw, xd, g1);

  // ---- D3: place (CSR finalize) ----
  CSRB q;
  q.st_ww = st_ww; q.st_wwr = st_wwr; q.st_wdr = st_wdr; q.st_wd = st_wd;
  q.c_ww = csr_ww; q.c_wwr = csr_wwr; q.c_wdr = csr_wdr; q.c_wd = csr_wd;
  q.rp_ww = rp_ww; q.rp_wwr = rp_wwr; q.rp_wdr = rp_wdr; q.rp_wd = rp_wd;
  q.bcnt = bcnt;
  place_kernel<<<BKT, 256, 0, stream>>>(q);

  // ---- D4: layer-1 gather (word act -> yB0, staging dead; doc -> xd1B) ----
  gather_all<<<(N_WORD + N_DOC + 3) / 4, 256, 0, stream>>>(
      yB2, xw1B, ydB, yBX, csr_ww, csr_wwr, csr_wdr, csr_wd,
      rp_ww, rp_wwr, rp_wdr, rp_wd, twA, tdA, bs1, b1 + 256,
      lin_w, lin_b, yB0, xd1B, nullptr, 1);

  // ---- D5: layer-2 GEMM ----
  G6 g2;
  g2.B[0] = Bp2 + 0 * W2; g2.C[0] = (unsigned short*)twA;
  g2.B[1] = Bp2 + 1 * W2; g2.C[1] = (unsigned short*)yB2;
  g2.B[2] = Bp2 + 2 * W2; g2.C[2] = (unsigned short*)xw1B;
  g2.B[3] = Bp2 + 3 * W2; g2.C[3] = (unsigned short*)yBX;
  g2.B[4] = Bp2 + 5 * W2; g2.C[4] = (unsigned short*)tdA;
  g2.B[5] = Bp2 + 4 * W2; g2.C[5] = (unsigned short*)ydB;
  gemm2_kernel<<<NSTRIP, 256, 0, stream>>>(yB0, xd1B, g2);

  // ---- D6: layer-2 gather + fused readout ----
  gather_all<<<(N_WORD + N_DOC + 3) / 4, 256, 0, stream>>>(
      yB2, xw1B, ydB, yBX, csr_ww, csr_wwr, csr_wdr, csr_wd,
      rp_ww, rp_wwr, rp_wdr, rp_wd, twA, tdA, bs2, b2 + 256,
      lin_w, lin_b, nullptr, nullptr, out, 2);
}

// Round 15
// 399.989 us; speedup vs baseline: 1.0221x; 1.0221x over previous
//
#include <hip/hip_runtime.h>
#include <math.h>

#define N_WORD 50000
#define N_DOC  10000
#define E_WW   800000
#define E_WD   320000
#define D_IN   256
#define D_H    128

#define NPB    256            // nodes per bucket
#define NBK_W  196            // ceil(50000/256)
#define NBK_D  40             // ceil(10000/256)
#define BKT    (3 * NBK_W + NBK_D)   // 628 buckets total
#define EPB    8192           // edges per bin block (LDS-sorted)
#define NBLK_WW 98            // ceil(800000/8192)
#define NBLK_WD 40            // ceil(320000/8192)
#define NBLK_TOT (2 * NBLK_WW + 2 * NBLK_WD)   // 276
#define PACK_BLKS 145

// per-bucket staging caps (binomial mean + >10 sigma; graph fixed by seed)
#define CAP_WW  4736          // mean 4082, sigma ~64
#define CAP_WDR 2176          // mean 1633, sigma ~40
#define CAP_WD  8960          // mean 8000, sigma ~89

#define WSTRIP ((N_WORD + 63) / 64)  // 782
#define DSTRIP ((N_DOC + 63) / 64)   // 157
#define NSTRIP (WSTRIP + DSTRIP)     // 939

typedef __attribute__((ext_vector_type(8))) short short8;
typedef __attribute__((ext_vector_type(4))) float f32x4;

__device__ inline unsigned short f2bf(float f) {  // fp32 -> bf16 bits, RNE
  unsigned u = __float_as_uint(f);
  u = (u + 0x7fffu + ((u >> 16) & 1u)) >> 16;
  return (unsigned short)u;
}

// ---------------- GEMM body: register-resident A fragments, no LDS ----------
struct G6 { const short* B[6]; unsigned short* C[6]; };

template <int ABF, int K>
__device__ void gemm_body(const void* __restrict__ Aw, const void* __restrict__ Ad,
                          const G6& g, int blk) {
  constexpr int KT = K >> 5;
  int wid = threadIdx.x >> 6, lane = threadIdx.x & 63;
  const void* A; int M, row0, h0, h1;
  if (blk < WSTRIP) { A = Aw; M = N_WORD; row0 = blk << 6; h0 = 0; h1 = 4; }
  else { A = Ad; M = N_DOC; row0 = (blk - WSTRIP) << 6; h0 = 4; h1 = 6; }
  int r = lane & 15, quad = lane >> 4;
  int m0 = row0 + wid * 16;
  int mA = m0 + r; if (mA >= M) mA = M - 1;   // clamp: garbage rows never stored
  short8 afr[KT];
  if (ABF) {
    const short* ap = (const short*)A + (size_t)mA * K + quad * 8;
#pragma unroll
    for (int kt = 0; kt < KT; ++kt) afr[kt] = *(const short8*)(ap + kt * 32);
  } else {
    const float* ap = (const float*)A + (size_t)mA * K + quad * 8;
#pragma unroll
    for (int kt = 0; kt < KT; ++kt) {
      float4 a0 = *(const float4*)(ap + kt * 32);
      float4 a1 = *(const float4*)(ap + kt * 32 + 4);
      short8 v;
      v[0] = (short)f2bf(a0.x); v[1] = (short)f2bf(a0.y);
      v[2] = (short)f2bf(a0.z); v[3] = (short)f2bf(a0.w);
      v[4] = (short)f2bf(a1.x); v[5] = (short)f2bf(a1.y);
      v[6] = (short)f2bf(a1.z); v[7] = (short)f2bf(a1.w);
      afr[kt] = v;
    }
  }
  for (int h = h0; h < h1; ++h) {
    const short* Bp = g.B[h];
    f32x4 acc[8];
#pragma unroll
    for (int nt = 0; nt < 8; ++nt) acc[nt] = (f32x4){0.f, 0.f, 0.f, 0.f};
#pragma unroll
    for (int kt = 0; kt < KT; ++kt) {
      const short* bbase = Bp + ((size_t)kt * 4096) + lane * 8;
#pragma unroll
      for (int nt = 0; nt < 8; ++nt) {
        short8 bf = *(const short8*)(bbase + (size_t)nt * 512);
        acc[nt] = __builtin_amdgcn_mfma_f32_16x16x32_bf16(afr[kt], bf, acc[nt], 0, 0, 0);
      }
    }
    // C/D: col = lane&15, row = quad*4 + rr  [m89-verified]
    unsigned short* C = g.C[h];
#pragma unroll
    for (int nt = 0; nt < 8; ++nt)
#pragma unroll
      for (int rr = 0; rr < 4; ++rr) {
        int row = m0 + quad * 4 + rr;
        if (row < M) C[(size_t)row * 128 + nt * 16 + r] = f2bf(acc[nt][rr]);
      }
  }
}

// ---------------- prep: weight pack + bias combine + bcnt zero ---------------
__global__ __launch_bounds__(256) void prep_kernel(
    const float* __restrict__ Ws1, const float* __restrict__ Wn1,
    const float* __restrict__ Ws2, const float* __restrict__ Wn2,
    short* __restrict__ Bp1, short* __restrict__ Bp2,
    const float* __restrict__ b1, const float* __restrict__ b2,
    float* __restrict__ bs1, float* __restrict__ bs2, int* __restrict__ bcnt) {
  int b = blockIdx.x;
  if (b == PACK_BLKS) {               // zero block
    for (int i = threadIdx.x; i < BKT; i += 256) bcnt[i] = 0;
    return;
  }
  int tid = b * 256 + threadIdx.x;
  const int L1T = 6 * 4096;
  const int L2T = 6 * 2048;
  if (tid >= L1T + L2T) {             // bias combine tail
    int t = tid - (L1T + L2T);
    if (t < 128) bs1[t] = b1[t] + b1[128 + t] + b1[384 + t];
    else if (t < 256) { int u = t - 128; bs2[u] = b2[u] + b2[128 + u] + b2[384 + u]; }
    return;
  }
  const float *src0, *src1 = nullptr, *src2 = nullptr;
  short* dstp;
  int kt, nt, lane;
  if (tid < L1T) {
    int mat = tid / 4096, rem = tid % 4096;
    kt = rem / 512; nt = (rem / 64) % 8; lane = rem % 64;
    const int W1 = 256 * 128;
    if (mat == 0) { src0 = Ws1; src1 = Ws1 + W1; src2 = Ws1 + 3 * W1; }
    else if (mat <= 4) src0 = Wn1 + (size_t)(mat - 1) * W1;
    else src0 = Ws1 + 2 * W1;
    dstp = Bp1 + (size_t)mat * W1 + ((size_t)(kt * 8 + nt) * 64 + lane) * 8;
  } else {
    int t2 = tid - L1T;
    int mat = t2 / 2048, rem = t2 % 2048;
    kt = rem / 512; nt = (rem / 64) % 8; lane = rem % 64;
    const int W2 = 128 * 128;
    if (mat == 0) { src0 = Ws2; src1 = Ws2 + W2; src2 = Ws2 + 3 * W2; }
    else if (mat <= 4) src0 = Wn2 + (size_t)(mat - 1) * W2;
    else src0 = Ws2 + 2 * W2;
    dstp = Bp2 + (size_t)mat * W2 + ((size_t)(kt * 8 + nt) * 64 + lane) * 8;
  }
  int n = nt * 16 + (lane & 15);
  int kb = kt * 32 + (lane >> 4) * 8;
  short8 v;
#pragma unroll
  for (int j = 0; j < 8; ++j) {
    float f = src0[(size_t)(kb + j) * 128 + n];
    if (src1) f += src1[(size_t)(kb + j) * 128 + n] + src2[(size_t)(kb + j) * 128 + n];
    v[j] = (short)f2bf(f);
  }
  *(short8*)dstp = v;
}

// ---------------- fused [LDS-sorted bin] || layer-1 GEMM ---------------------
// bin: block hist -> LDS scan -> global run reservation -> LDS counting-sort
// -> linear sweep writes staging COALESCED (the r14 93MB write-amp killer).
// Entry encoding in LDS: (bk<<24) | (node_lo<<16) | src;  staging keeps low 24b.
__device__ inline void rel_map(int b, const int* wwd, const int* wwrd, const int* wdrd,
                               const int* wdd, const int*& dst, int& E, int& gbase, int& lb) {
  if (b < NBLK_WW) { dst = wwd; E = E_WW; gbase = 0; lb = b; }
  else if (b < 2 * NBLK_WW) { dst = wwrd; E = E_WW; gbase = NBK_W; lb = b - NBLK_WW; }
  else if (b < 2 * NBLK_WW + NBLK_WD) { dst = wdrd; E = E_WD; gbase = 2 * NBK_W; lb = b - 2 * NBLK_WW; }
  else { dst = wdd; E = E_WD; gbase = 3 * NBK_W; lb = b - 2 * NBLK_WW - NBLK_WD; }
}

struct BinLDS {
  unsigned buf[EPB];          // 32 KB sorted edge buffer
  int hist[NBK_W];
  int lofs[NBK_W];
  int gofs[NBK_W];            // global run base - local offset
  int lcur[NBK_W];
  int sm[256];
};

__global__ __launch_bounds__(256, 4) void bin_gemm1(
    const int* wws, const int* wwd, const int* wwrs, const int* wwrd,
    const int* wdrs, const int* wdrd, const int* wds, const int* wdd,
    int* bcnt, unsigned* st_ww, unsigned* st_wwr, unsigned* st_wdr, unsigned* st_wd,
    const float* __restrict__ Aw, const float* __restrict__ Ad, G6 g) {
  __shared__ BinLDS L;                // ~36 KB; gemm branch unused -> 4 blk/CU
  int b = blockIdx.x;
  if (b >= NBLK_TOT) {
    gemm_body<0, 256>(Aw, Ad, g, b - NBLK_TOT);
    return;
  }
  const int* dst; int E, gbase, lb;
  rel_map(b, wwd, wwrd, wdrd, wdd, dst, E, gbase, lb);
  const int* src; unsigned* st; int cap;
  if (b < NBLK_WW) { src = wws; st = st_ww; cap = CAP_WW; }
  else if (b < 2 * NBLK_WW) { src = wwrs; st = st_wwr; cap = CAP_WW; }
  else if (b < 2 * NBLK_WW + NBLK_WD) { src = wdrs; st = st_wdr; cap = CAP_WDR; }
  else { src = wds; st = st_wd; cap = CAP_WD; }
  int tid = threadIdx.x;
  int e0 = lb * EPB;
  int ecnt = E - e0; if (ecnt > EPB) ecnt = EPB;
  if (tid < NBK_W) L.hist[tid] = 0;
  __syncthreads();
  // pass 1: histogram (dst cached in VGPRs for pass 2)
  int dcache[EPB / 256];
#pragma unroll
  for (int k = 0; k < EPB / 256; ++k) {
    int i = e0 + k * 256 + tid;
    int d = (i < E) ? dst[i] : -1;
    dcache[k] = d;
    if (d >= 0) atomicAdd(&L.hist[d >> 8], 1);
  }
  __syncthreads();
  // scan hist -> exclusive local offsets; reserve global runs
  {
    int v = (tid < NBK_W) ? L.hist[tid] : 0;
    L.sm[tid] = v;
    __syncthreads();
    for (int o = 1; o < 256; o <<= 1) {
      int add = (tid >= o) ? L.sm[tid - o] : 0;
      __syncthreads();
      L.sm[tid] += add;
      __syncthreads();
    }
    if (tid < NBK_W) {
      int ex = L.sm[tid] - v;
      L.lofs[tid] = ex;
      L.lcur[tid] = ex;
      int base = v ? atomicAdd(&bcnt[gbase + tid], v) : 0;
      L.gofs[tid] = (int)((size_t)tid * cap) + base - ex;
    }
  }
  __syncthreads();
  // pass 2: counting-sort scatter into LDS
#pragma unroll
  for (int k = 0; k < EPB / 256; ++k) {
    int d = dcache[k];
    if (d >= 0) {
      int i = e0 + k * 256 + tid;
      int bk = d >> 8;
      int p = atomicAdd(&L.lcur[bk], 1);
      L.buf[p] = ((unsigned)bk << 24) | ((unsigned)(d & 255) << 16) |
                 (unsigned)(src[i] & 0xFFFF);
    }
  }
  __syncthreads();
  // coalesced writeout: consecutive LDS entries -> consecutive staging addrs
#pragma unroll
  for (int k = 0; k < EPB / 256; ++k) {
    int p = k * 256 + tid;
    if (p < ecnt) {
      unsigned e = L.buf[p];
      st[L.gofs[e >> 24] + p] = e & 0x00FFFFFFu;
    }
  }
}

// ---------------- place: one block per 256-node bucket -----------------------
struct CSRB {
  const unsigned *st_ww, *st_wwr, *st_wdr, *st_wd;
  unsigned short *c_ww, *c_wwr, *c_wdr, *c_wd;
  int *rp_ww, *rp_wwr, *rp_wdr, *rp_wd;
  const int* bcnt;
};

__global__ __launch_bounds__(256) void place_kernel(CSRB q) {
  __shared__ int cnt[256], off[256], sm[256];
  int g = blockIdx.x;
  const unsigned* st; unsigned short* csr; int* rp; int relFirst, relLast, n, cap, Etot;
  if (g < NBK_W)            { st = q.st_ww;  csr = q.c_ww;  rp = q.rp_ww;  relFirst = 0;         relLast = NBK_W - 1;     n = N_WORD; cap = CAP_WW;  Etot = E_WW; }
  else if (g < 2 * NBK_W)   { st = q.st_wwr; csr = q.c_wwr; rp = q.rp_wwr; relFirst = NBK_W;     relLast = 2 * NBK_W - 1; n = N_WORD; cap = CAP_WW;  Etot = E_WW; }
  else if (g < 3 * NBK_W)   { st = q.st_wdr; csr = q.c_wdr; rp = q.rp_wdr; relFirst = 2 * NBK_W; relLast = 3 * NBK_W - 1; n = N_WORD; cap = CAP_WDR; Etot = E_WD; }
  else                      { st = q.st_wd;  csr = q.c_wd;  rp = q.rp_wd;  relFirst = 3 * NBK_W; relLast = BKT - 1;       n = N_DOC;  cap = CAP_WD;  Etot = E_WD; }
  int cb = g - relFirst;
  int tid = threadIdx.x;
  int v = (tid < cb) ? q.bcnt[relFirst + tid] : 0;
  sm[tid] = v;
  __syncthreads();
  for (int o = 128; o > 0; o >>= 1) {
    if (tid < o) sm[tid] += sm[tid + o];
    __syncthreads();
  }
  int bstart = sm[0];
  if (g == relLast && tid == 0) rp[n] = Etot;   // tail sentinel
  __syncthreads();
  int node_base = cb << 8;
  int node_cnt = n - node_base; if (node_cnt > NPB) node_cnt = NPB;
  int ecnt = q.bcnt[g];
  const unsigned* w = st + (size_t)cb * cap;
  cnt[tid] = 0;
  __syncthreads();
  for (int j = tid; j < ecnt; j += 256) atomicAdd(&cnt[w[j] >> 16], 1);
  __syncthreads();
  int c = cnt[tid];
  sm[tid] = c;
  __syncthreads();
  for (int o = 1; o < 256; o <<= 1) {
    int add = (tid >= o) ? sm[tid - o] : 0;
    __syncthreads();
    sm[tid] += add;
    __syncthreads();
  }
  int ex = sm[tid] - c;
  off[tid] = ex;
  if (tid < node_cnt) rp[node_base + tid] = bstart + ex;
  __syncthreads();
  for (int j = tid; j < ecnt; j += 256) {
    unsigned e = w[j];
    int p = atomicAdd(&off[e >> 16], 1);
    csr[bstart + p] = (unsigned short)(e & 0xFFFFu);
  }
}

__global__ __launch_bounds__(256, 6) void gemm2_kernel(
    const void* __restrict__ Aw, const void* __restrict__ Ad, G6 g) {
  gemm_body<1, 128>(Aw, Ad, g, blockIdx.x);
}

// ---------------- merged gather: readlane scalar-base loads, 8-deep MLP ------
__device__ inline void accum_rel(const unsigned* __restrict__ y,
                                 const unsigned short* __restrict__ csr,
                                 int beg, int end, int lane, float& f0, float& f1) {
  float a0 = 0.f, a1 = 0.f;
  for (int base = beg; base < end; base += 64) {
    int cnt = end - base; if (cnt > 64) cnt = 64;
    int ld = base + lane; if (ld >= end) ld = end - 1;
    int idx = csr[ld];                 // 64 indices per coalesced 128B load
    int j = 0;
    for (; j + 7 < cnt; j += 8) {      // 8 loads in flight
      unsigned u[8];
#pragma unroll
      for (int k = 0; k < 8; ++k) {
        int s = __builtin_amdgcn_readlane(idx, j + k);   // SGPR row -> scalar base
        u[k] = y[((size_t)s << 6) + lane];
      }
#pragma unroll
      for (int k = 0; k < 8; ++k) {
        a0 += __uint_as_float(u[k] << 16);
        a1 += __uint_as_float(u[k] & 0xffff0000u);
      }
    }
    for (; j < cnt; ++j) {
      int s = __builtin_amdgcn_readlane(idx, j);
      unsigned uu = y[((size_t)s << 6) + lane];
      a0 += __uint_as_float(uu << 16);
      a1 += __uint_as_float(uu & 0xffff0000u);
    }
  }
  int deg = end - beg;
  float inv = 1.0f / (float)(deg > 1 ? deg : 1);
  f0 += a0 * inv;
  f1 += a1 * inv;
}

// mode 1: write bf16 activations; mode 2: fused linear+sigmoid readout.
__global__ __launch_bounds__(256) void gather_all(
    const unsigned* __restrict__ y_ww, const unsigned* __restrict__ y_wwr,
    const unsigned* __restrict__ y_wdr, const unsigned* __restrict__ y_wd,
    const unsigned short* __restrict__ c_ww, const unsigned short* __restrict__ c_wwr,
    const unsigned short* __restrict__ c_wdr, const unsigned short* __restrict__ c_wd,
    const int* __restrict__ r_ww, const int* __restrict__ r_wwr,
    const int* __restrict__ r_wdr, const int* __restrict__ r_wd,
    const unsigned* __restrict__ tW, const unsigned* __restrict__ tD,
    const float* __restrict__ bW, const float* __restrict__ bD,
    const float* __restrict__ lw, const float* __restrict__ lb,
    unsigned* __restrict__ oW16, unsigned* __restrict__ oD16,
    float* __restrict__ oF, int mode) {
  int gn = (blockIdx.x << 2) + (threadIdx.x >> 6);
  if (gn >= N_WORD + N_DOC) return;
  int lane = threadIdx.x & 63;
  float f0, f1;
  if (gn < N_WORD) {
    int node = gn;
    unsigned tu = tW[((size_t)node << 6) + lane];     // bf16 self term
    f0 = __uint_as_float(tu << 16);
    f1 = __uint_as_float(tu & 0xffff0000u);
    accum_rel(y_ww, c_ww, r_ww[node], r_ww[node + 1], lane, f0, f1);
    accum_rel(y_wwr, c_wwr, r_wwr[node], r_wwr[node + 1], lane, f0, f1);
    accum_rel(y_wdr, c_wdr, r_wdr[node], r_wdr[node + 1], lane, f0, f1);
    float2 bv = ((const float2*)bW)[lane];
    f0 = fmaxf(f0 + bv.x, 0.f);
    f1 = fmaxf(f1 + bv.y, 0.f);
    if (mode == 1) {
      oW16[((size_t)node << 6) + lane] = (unsigned)f2bf(f0) | ((unsigned)f2bf(f1) << 16);
    } else {
      float2 lv = ((const float2*)lw)[lane];
      float s = f0 * lv.x + f1 * lv.y;
#pragma unroll
      for (int off = 32; off > 0; off >>= 1) s += __shfl_xor(s, off);
      if (lane == 0) oF[node] = 1.0f / (1.0f + expf(-(s + lb[0])));
    }
  } else {
    int node = gn - N_WORD;
    unsigned tu = tD[((size_t)node << 6) + lane];
    f0 = __uint_as_float(tu << 16);
    f1 = __uint_as_float(tu & 0xffff0000u);
    accum_rel(y_wd, c_wd, r_wd[node], r_wd[node + 1], lane, f0, f1);
    float2 bv = ((const float2*)bD)[lane];
    f0 = fmaxf(f0 + bv.x, 0.f);
    f1 = fmaxf(f1 + bv.y, 0.f);
    if (mode == 1) {
      oD16[((size_t)node << 6) + lane] = (unsigned)f2bf(f0) | ((unsigned)f2bf(f1) << 16);
    } else {
      float2 lv = ((const float2*)lw)[lane];
      float s = f0 * lv.x + f1 * lv.y;
#pragma unroll
      for (int off = 32; off > 0; off >>= 1) s += __shfl_xor(s, off);
      if (lane == 0) oF[N_WORD + node] = 1.0f / (1.0f + expf(-(s + lb[0])));
    }
  }
}

// ---------------------------------------------------------------------------
extern "C" void kernel_launch(void* const* d_in, const int* in_sizes, int n_in,
                              void* d_out, int out_size, void* d_ws, size_t ws_size,
                              hipStream_t stream) {
  const float* xw      = (const float*)d_in[0];
  const float* xd      = (const float*)d_in[1];
  const int*   ww_src  = (const int*)d_in[2];
  const int*   ww_dst  = (const int*)d_in[3];
  const int*   wwr_src = (const int*)d_in[4];
  const int*   wwr_dst = (const int*)d_in[5];
  const int*   wd_src  = (const int*)d_in[6];
  const int*   wd_dst  = (const int*)d_in[7];
  const int*   wdr_src = (const int*)d_in[8];
  const int*   wdr_dst = (const int*)d_in[9];
  const float* Ws1     = (const float*)d_in[10];
  const float* Wn1     = (const float*)d_in[11];
  const float* b1      = (const float*)d_in[12];
  const float* Ws2     = (const float*)d_in[13];
  const float* Wn2     = (const float*)d_in[14];
  const float* b2      = (const float*)d_in[15];
  const float* lin_w   = (const float*)d_in[16];
  const float* lin_b   = (const float*)d_in[17];
  float* out = (float*)d_out;

  // ---- workspace carve (~91 MB; staging aliases yB0/yB1 pre-place) ----
  char* p = (char*)d_ws;
  auto alloc = [&](size_t nbytes) {
    char* r = p;
    p += (nbytes + 255) & ~(size_t)255;
    return r;
  };
  unsigned* twA  = (unsigned*)alloc((size_t)N_WORD * D_H * 2);  // bf16 self acc
  unsigned* tdA  = (unsigned*)alloc((size_t)N_DOC * D_H * 2);
  unsigned* xw1B = (unsigned*)alloc((size_t)N_WORD * D_H * 2);
  unsigned* xd1B = (unsigned*)alloc((size_t)N_DOC * D_H * 2);
  unsigned* yB0 = (unsigned*)alloc((size_t)N_WORD * D_H * 2);
  unsigned* yB1 = (unsigned*)alloc((size_t)N_WORD * D_H * 2);
  unsigned* yB2 = (unsigned*)alloc((size_t)N_WORD * D_H * 2);
  unsigned* ydB = (unsigned*)alloc((size_t)N_DOC * D_H * 2);
  unsigned short* csr_ww  = (unsigned short*)alloc((size_t)E_WW * 2);
  unsigned short* csr_wwr = (unsigned short*)alloc((size_t)E_WW * 2);
  unsigned short* csr_wdr = (unsigned short*)alloc((size_t)E_WD * 2);
  unsigned short* csr_wd  = (unsigned short*)alloc((size_t)E_WD * 2);
  int* rp_ww  = (int*)alloc((size_t)(N_WORD + 1) * 4);
  int* rp_wwr = (int*)alloc((size_t)(N_WORD + 1) * 4);
  int* rp_wdr = (int*)alloc((size_t)(N_WORD + 1) * 4);
  int* rp_wd  = (int*)alloc((size_t)(N_DOC + 1) * 4);
  short* Bp1 = (short*)alloc((size_t)6 * 256 * 128 * 2);
  short* Bp2 = (short*)alloc((size_t)6 * 128 * 128 * 2);
  int* bcnt  = (int*)alloc((size_t)BKT * 4);
  float* bs1 = (float*)alloc(D_H * 4);
  float* bs2 = (float*)alloc(D_H * 4);
  unsigned* yBX = (unsigned*)alloc((size_t)N_WORD * D_H * 2);   // wd-neigh out
  // staging aliases (read by place; dead before gather1 writes yB0)
  unsigned* st_ww  = yB0;
  unsigned* st_wwr = st_ww + (size_t)NBK_W * CAP_WW;
  unsigned* st_wdr = yB1;
  unsigned* st_wd  = st_wdr + (size_t)NBK_W * CAP_WDR;

  const int W1 = 256 * 128;
  const int W2 = 128 * 128;

  // ---- D1: prep (pack + bias + bcnt zero) ----
  prep_kernel<<<PACK_BLKS + 1, 256, 0, stream>>>(
      Ws1, Wn1, Ws2, Wn2, Bp1, Bp2, b1, b2, bs1, bs2, bcnt);

  // ---- D2: LDS-sorted bin || layer-1 GEMM ----
  G6 g1;
  g1.B[0] = Bp1 + 0 * W1; g1.C[0] = (unsigned short*)twA;   // word self
  g1.B[1] = Bp1 + 1 * W1; g1.C[1] = (unsigned short*)yB2;   // ww neigh
  g1.B[2] = Bp1 + 2 * W1; g1.C[2] = (unsigned short*)xw1B;  // wwr neigh
  g1.B[3] = Bp1 + 3 * W1; g1.C[3] = (unsigned short*)yBX;   // wd neigh
  g1.B[4] = Bp1 + 5 * W1; g1.C[4] = (unsigned short*)tdA;   // doc self
  g1.B[5] = Bp1 + 4 * W1; g1.C[5] = (unsigned short*)ydB;   // wdr neigh
  bin_gemm1<<<NBLK_TOT + NSTRIP, 256, 0, stream>>>(
      ww_src, ww_dst, wwr_src, wwr_dst, wdr_src, wdr_dst, wd_src, wd_dst,
      bcnt, st_ww, st_wwr, st_wdr, st_wd, xw, xd, g1);

  // ---- D3: place (CSR finalize) ----
  CSRB q;
  q.st_ww = st_ww; q.st_wwr = st_wwr; q.st_wdr = st_wdr; q.st_wd = st_wd;
  q.c_ww = csr_ww; q.c_wwr = csr_wwr; q.c_wdr = csr_wdr; q.c_wd = csr_wd;
  q.rp_ww = rp_ww; q.rp_wwr = rp_wwr; q.rp_wdr = rp_wdr; q.rp_wd = rp_wd;
  q.bcnt = bcnt;
  place_kernel<<<BKT, 256, 0, stream>>>(q);

  // ---- D4: layer-1 gather (word act -> yB0, staging dead; doc -> xd1B) ----
  gather_all<<<(N_WORD + N_DOC + 3) / 4, 256, 0, stream>>>(
      yB2, xw1B, ydB, yBX, csr_ww, csr_wwr, csr_wdr, csr_wd,
      rp_ww, rp_wwr, rp_wdr, rp_wd, twA, tdA, bs1, b1 + 256,
      lin_w, lin_b, yB0, xd1B, nullptr, 1);

  // ---- D5: layer-2 GEMM ----
  G6 g2;
  g2.B[0] = Bp2 + 0 * W2; g2.C[0] = (unsigned short*)twA;
  g2.B[1] = Bp2 + 1 * W2; g2.C[1] = (unsigned short*)yB2;
  g2.B[2] = Bp2 + 2 * W2; g2.C[2] = (unsigned short*)xw1B;
  g2.B[3] = Bp2 + 3 * W2; g2.C[3] = (unsigned short*)yBX;
  g2.B[4] = Bp2 + 5 * W2; g2.C[4] = (unsigned short*)tdA;
  g2.B[5] = Bp2 + 4 * W2; g2.C[5] = (unsigned short*)ydB;
  gemm2_kernel<<<NSTRIP, 256, 0, stream>>>(yB0, xd1B, g2);

  // ---- D6: layer-2 gather + fused readout ----
  gather_all<<<(N_WORD + N_DOC + 3) / 4, 256, 0, stream>>>(
      yB2, xw1B, ydB, yBX, csr_ww, csr_wwr, csr_wdr, csr_wd,
      rp_ww, rp_wwr, rp_wdr, rp_wd, twA, tdA, bs2, b2 + 256,
      lin_w, lin_b, nullptr, nullptr, out, 2);
}